// Round 2
// baseline (778.151 us; speedup 1.0000x reference)
//
#include <hip/hip_runtime.h>
#include <hip/hip_bf16.h>
#include <cstdint>

// ---- problem constants (bs=4, slen=1024 -> T=4096; dim=2048; hidden=1024; E=8; top-2) ----
#define TTOK   4096
#define DIM    2048
#define HID    1024
#define NEXP   8          // routed experts
#define GROWS  12288      // TTOK*2 routed rows + TTOK shared rows

typedef __attribute__((ext_vector_type(8))) __bf16 bf16x8;
typedef __attribute__((ext_vector_type(4))) float  f32x4;

__device__ __forceinline__ void glds16(const void* g, void* l) {
  __builtin_amdgcn_global_load_lds((const __attribute__((address_space(1))) void*)g,
                                   (__attribute__((address_space(3))) void*)l,
                                   16, 0, 0);
}

// raw barrier (no compiler-inserted vmcnt(0) drain); memory clobbers pin LDS/glds ordering
#define BAR() do { asm volatile("" ::: "memory"); __builtin_amdgcn_s_barrier(); \
                   asm volatile("" ::: "memory"); } while (0)

// ---------------- weight conversion ----------------
// w13cat (9 x 2048 x 2048): rows INTERLEAVED per expert: new_r = 2j -> w1[j], 2j+1 -> w3[j]
// so GEMM1 output col pairs (2j,2j+1) = (h1_j,h3_j) -> silu fused in GEMM1 epilogue via shfl_xor(1).
// w2cat (9 x 2048 x 1024) unchanged.
__global__ void convert_w(const float* __restrict__ w1, const float* __restrict__ w2,
                          const float* __restrict__ w3, const float* __restrict__ ws1,
                          const float* __restrict__ ws2, const float* __restrict__ ws3,
                          __bf16* __restrict__ w13, __bf16* __restrict__ w2c) {
  const int N1 = 9 * 2048 * 2048 / 8;   // 16B-out chunks for w13
  const int N2 = 9 * 2048 * 1024 / 8;   // chunks for w2c
  int s = blockIdx.x * 256 + threadIdx.x;
  const float* src;
  __bf16* dst;
  if (s < N1) {
    int e  = s / 524288;            // 2048*2048/8
    int r  = (s % 524288) / 256;    // source row 0..2047
    int c  = (s % 256) * 8;
    int nr;
    if (r < 1024) { src = (e < 8 ? w1 + ((size_t)e * 1024 + r) * 2048 : ws1 + (size_t)r * 2048) + c;
                    nr = 2 * r; }
    else          { src = (e < 8 ? w3 + ((size_t)e * 1024 + (r - 1024)) * 2048 : ws3 + (size_t)(r - 1024) * 2048) + c;
                    nr = 2 * (r - 1024) + 1; }
    dst = w13 + ((size_t)e * 2048 + nr) * 2048 + c;
  } else {
    int s2 = s - N1;
    if (s2 >= N2) return;
    int e  = s2 / 262144;           // 2048*1024/8
    int r  = (s2 % 262144) / 128;   // row (d) 0..2047
    int c  = (s2 % 128) * 8;
    src = (e < 8 ? w2 + ((size_t)e * 2048 + r) * 1024 : ws2 + (size_t)r * 1024) + c;
    dst = w2c + ((size_t)e * 2048 + r) * 1024 + c;
  }
  float4 a = *(const float4*)(src);
  float4 b = *(const float4*)(src + 4);
  bf16x8 o;
  o[0]=(__bf16)a.x; o[1]=(__bf16)a.y; o[2]=(__bf16)a.z; o[3]=(__bf16)a.w;
  o[4]=(__bf16)b.x; o[5]=(__bf16)b.y; o[6]=(__bf16)b.z; o[7]=(__bf16)b.w;
  *(bf16x8*)dst = o;
}

// ---------------- router: one wave per token, fp32 logits, sigmoid, top-2 ----------------
__global__ void router_k(const float* __restrict__ x, const float* __restrict__ gw,
                         int* __restrict__ sel, float* __restrict__ sco, int* __restrict__ counts) {
  int t    = blockIdx.x * 4 + (threadIdx.x >> 6);
  int lane = threadIdx.x & 63;
  const float* xr = x + (size_t)t * DIM;
  float acc[NEXP];
  #pragma unroll
  for (int e = 0; e < NEXP; ++e) acc[e] = 0.f;
  for (int d = lane * 4; d < DIM; d += 256) {
    float4 xv = *(const float4*)(xr + d);
    #pragma unroll
    for (int e = 0; e < NEXP; ++e) {
      float4 gv = *(const float4*)(gw + (size_t)e * DIM + d);
      acc[e] += xv.x * gv.x + xv.y * gv.y + xv.z * gv.z + xv.w * gv.w;
    }
  }
  #pragma unroll
  for (int off = 32; off; off >>= 1)
    #pragma unroll
    for (int e = 0; e < NEXP; ++e) acc[e] += __shfl_xor(acc[e], off);
  if (lane == 0) {
    float s[NEXP];
    #pragma unroll
    for (int e = 0; e < NEXP; ++e) s[e] = 1.f / (1.f + expf(-acc[e]));
    int e0 = 0;
    #pragma unroll
    for (int e = 1; e < NEXP; ++e) if (s[e] > s[e0]) e0 = e;
    int e1 = (e0 == 0) ? 1 : 0;
    #pragma unroll
    for (int e = 0; e < NEXP; ++e) if (e != e0 && s[e] > s[e1]) e1 = e;
    sel[2 * t] = e0; sel[2 * t + 1] = e1;
    sco[2 * t] = s[e0]; sco[2 * t + 1] = s[e1];
    atomicAdd(&counts[e0], 1); atomicAdd(&counts[e1], 1);
  }
}

// ---------------- exclusive scan over 9 segments (expert 8 = shared, count TTOK) ----------------
__global__ void scan_k(const int* __restrict__ counts, int* __restrict__ offs) {
  if (threadIdx.x == 0 && blockIdx.x == 0) {
    int o = 0;
    for (int e = 0; e < NEXP; ++e) { offs[e] = o; o += counts[e]; }
    offs[NEXP] = o;            // == 8192
    offs[NEXP + 1] = o + TTOK; // == 12288
  }
}

// ---------------- gather: write score-scaled bf16 rows into compact segments ----------------
__global__ void gather_k(const float* __restrict__ x, const int* __restrict__ sel,
                         const float* __restrict__ sco, const int* __restrict__ offs,
                         int* __restrict__ cursor, int* __restrict__ token_rows,
                         __bf16* __restrict__ xg) {
  __shared__ int   rows[3];
  __shared__ float ss[3];
  int t = blockIdx.x;
  if (threadIdx.x == 0) {
    int e0 = sel[2 * t], e1 = sel[2 * t + 1];
    int r0 = offs[e0] + atomicAdd(&cursor[e0], 1);
    int r1 = offs[e1] + atomicAdd(&cursor[e1], 1);
    int r2 = 8192 + t; // shared segment starts at 8192 always
    rows[0] = r0; rows[1] = r1; rows[2] = r2;
    ss[0] = sco[2 * t]; ss[1] = sco[2 * t + 1]; ss[2] = 1.0f;
    token_rows[3 * t] = r0; token_rows[3 * t + 1] = r1; token_rows[3 * t + 2] = r2;
  }
  __syncthreads();
  int c = threadIdx.x * 8;
  float4 v0 = *(const float4*)(x + (size_t)t * DIM + c);
  float4 v1 = *(const float4*)(x + (size_t)t * DIM + c + 4);
  #pragma unroll
  for (int j = 0; j < 3; ++j) {
    float s = ss[j];
    bf16x8 o;
    o[0]=(__bf16)(v0.x*s); o[1]=(__bf16)(v0.y*s); o[2]=(__bf16)(v0.z*s); o[3]=(__bf16)(v0.w*s);
    o[4]=(__bf16)(v1.x*s); o[5]=(__bf16)(v1.y*s); o[6]=(__bf16)(v1.z*s); o[7]=(__bf16)(v1.w*s);
    *(bf16x8*)(xg + (size_t)rows[j] * DIM + c) = o;
  }
}

// ---------------- grouped NT GEMM, 256x256 tile, BK=64, 8 waves (2Mx4N), phase-split ----------------
// 8-phase-style schedule (T3+T4+T5): per K-tile, 4 phases of {ds_read subtile; s_barrier;
// setprio(1) 16xMFMA setprio(0); s_barrier}; next tile's 8 global_load_lds issued at iter start
// and waited with COUNTED s_waitcnt vmcnt(8) (never drains to 0 in main loop) + raw s_barrier.
// Trailing phase barrier guarantees all waves retired their ds_reads (lgkmcnt(0) precedes MFMA)
// before the next iteration's glds writes can land in that buffer.
// LDS: chunk j (16B) of tile-row r stored at slot j^(r&7); staging permutes the GLOBAL chunk
// fetched per lane (glds16 LDS dest is base+lane*16, fixed — m104). Measured 0 bank conflicts.
// XCD swizzle: 128 blocks per z, chunked 8x16, bm fastest within chunk -> B-panel L2 reuse.
// EPI=0: fused silu(h1)*h3 epilogue (w13 rows interleaved), writes bf16 h (GROWS x 1024).
// EPI=1: fp32 stores into split c2 buffers (no atomics).
template <int EPI>
__launch_bounds__(512, 2)
__global__ void gemm_nt(const __bf16* __restrict__ A, const __bf16* __restrict__ Bw,
                        __bf16* __restrict__ Hb, float* __restrict__ c2a, float* __restrict__ c2b,
                        const int* __restrict__ offs, int K_, int N_) {
  int z  = blockIdx.z;
  int o0 = offs[z];
  int ne = offs[z + 1] - o0;

  int flat = blockIdx.y * 16 + blockIdx.x;       // 0..127, ascending dispatch order (x fastest)
  int nid  = (flat & 7) * 16 + (flat >> 3);      // bijective (128 % 8 == 0), 8 XCD chunks of 16
  int bm   = nid & 15;                           // fastest within chunk -> B-panel reuse per XCD
  int bn   = nid >> 4;

  if (bm * 256 >= ne) return;

  const __bf16* Aseg = A  + (size_t)(o0 + bm * 256) * K_;
  const __bf16* Bseg = Bw + ((size_t)z * N_ + bn * 256) * K_;

  __shared__ __align__(16) __bf16 sA[2][256 * 64];   // 32 KiB each
  __shared__ __align__(16) __bf16 sB[2][256 * 64];   // total 128 KiB

  int tid  = threadIdx.x;
  int wave = tid >> 6, lane = tid & 63;
  int wm = wave & 1;        // M-half (rows wm*128..+128)
  int wn = wave >> 1;       // N-quarter (cols wn*64..+64)
  int fr = lane & 15;       // fragment row (m for A, n for B, also out col)
  int fq = lane >> 4;       // quad
  int sw = fr & 7;          // lane-constant XOR swizzle

  f32x4 acc[8][4];
  #pragma unroll
  for (int i = 0; i < 8; ++i)
    #pragma unroll
    for (int j = 0; j < 4; ++j) acc[i][j] = (f32x4){0.f, 0.f, 0.f, 0.f};

#define STAGE(buf, kbase)                                                     \
  {                                                                           \
    _Pragma("unroll")                                                         \
    for (int it = 0; it < 4; ++it) {                                          \
      int s   = it * 512 + tid;                                               \
      int row = s >> 3;                                                       \
      int c8  = (s & 7) ^ (row & 7);                                          \
      glds16(Aseg + (size_t)row * K_ + (kbase) + c8 * 8, &sA[buf][s * 8]);    \
      glds16(Bseg + (size_t)row * K_ + (kbase) + c8 * 8, &sB[buf][s * 8]);    \
    }                                                                         \
  }

  // prologue: stage tile 0 into buf 0
  STAGE(0, 0)
  asm volatile("s_waitcnt vmcnt(0)" ::: "memory");
  BAR();

  const int nk = K_ >> 6;
  for (int t = 0; t < nk; ++t) {
    int cur = t & 1;
    if (t + 1 < nk) {
      STAGE(cur ^ 1, (t + 1) << 6)                       // 8 loads in flight across phases
      asm volatile("s_waitcnt vmcnt(8)" ::: "memory");   // previous tile's 8 landed (own)
    } else {
      asm volatile("s_waitcnt vmcnt(0)" ::: "memory");
    }
    BAR();                                               // all waves: buf[cur] fully landed

    const __bf16* sAc = &sA[cur][0];
    const __bf16* sBc = &sB[cur][0];
    #pragma unroll
    for (int kk = 0; kk < 2; ++kk) {
      int slot = ((kk * 4 + fq) ^ sw) * 8;
      bf16x8 bb[4];
      #pragma unroll
      for (int i = 0; i < 4; ++i)
        bb[i] = *(const bf16x8*)(sBc + (wn * 64 + i * 16 + fr) * 64 + slot);
      #pragma unroll
      for (int mh = 0; mh < 2; ++mh) {
        bf16x8 af[4];
        #pragma unroll
        for (int i = 0; i < 4; ++i)
          af[i] = *(const bf16x8*)(sAc + (wm * 128 + (mh * 4 + i) * 16 + fr) * 64 + slot);
        BAR();                                           // phase alignment (role-split for setprio)
        __builtin_amdgcn_s_setprio(1);
        #pragma unroll
        for (int i = 0; i < 4; ++i)
          #pragma unroll
          for (int j = 0; j < 4; ++j)
            acc[mh * 4 + i][j] =
                __builtin_amdgcn_mfma_f32_16x16x32_bf16(af[i], bb[j], acc[mh * 4 + i][j], 0, 0, 0);
        __builtin_amdgcn_s_setprio(0);
        BAR();                                           // all waves' ds_reads of this phase retired
      }
    }
  }
#undef STAGE

  // epilogue: C/D layout col = lane&15 (=fr), row = fq*4 + r   [m89/m91 verified]
  #pragma unroll
  for (int mi = 0; mi < 8; ++mi) {
    #pragma unroll
    for (int r = 0; r < 4; ++r) {
      int rl = bm * 256 + wm * 128 + mi * 16 + fq * 4 + r;
      bool ok = rl < ne;
      int grow = o0 + rl;
      if (EPI == 0) {
        #pragma unroll
        for (int ni = 0; ni < 4; ++ni) {
          float v = acc[mi][ni][r];
          float o = __shfl_xor(v, 1);          // partner holds the other half of (h1,h3) pair
          float h1 = (fr & 1) ? o : v;
          float h3 = (fr & 1) ? v : o;
          float g  = h1 / (1.f + expf(-h1)) * h3;
          if (ok && !(fr & 1)) {
            int hcol = bn * 128 + wn * 32 + ni * 8 + (fr >> 1);
            Hb[(size_t)grow * 1024 + hcol] = (__bf16)g;
          }
        }
      } else {
        if (ok) {
          float* dst = (grow < 8192) ? (c2a + (size_t)grow * 2048)
                                     : (c2b + (size_t)(grow - 8192) * 2048);
          #pragma unroll
          for (int ni = 0; ni < 4; ++ni) {
            int col = bn * 256 + wn * 64 + ni * 16 + fr;
            dst[col] = acc[mi][ni][r];
          }
        }
      }
    }
  }
}

// ---------------- combine: out[t] = c2[r0] + c2[r1] + c2[r2] (fp32, deterministic) ----------------
__global__ void combine_k(const float* __restrict__ c2a, const float* __restrict__ c2b,
                          const int* __restrict__ token_rows, float* __restrict__ out) {
  __shared__ int rr[3];
  int t = blockIdx.x;
  if (threadIdx.x < 3) rr[threadIdx.x] = token_rows[3 * t + threadIdx.x];
  __syncthreads();
  int c = threadIdx.x * 8;
  const float* p0 = c2a + (size_t)rr[0] * 2048 + c;
  const float* p1 = c2a + (size_t)rr[1] * 2048 + c;
  const float* p2 = c2b + (size_t)(rr[2] - 8192) * 2048 + c;
  float4 a0 = *(const float4*)p0,       a1 = *(const float4*)p1,       a2 = *(const float4*)p2;
  float4 b0 = *(const float4*)(p0 + 4), b1 = *(const float4*)(p1 + 4), b2 = *(const float4*)(p2 + 4);
  float4 oa, ob;
  oa.x = a0.x + a1.x + a2.x; oa.y = a0.y + a1.y + a2.y;
  oa.z = a0.z + a1.z + a2.z; oa.w = a0.w + a1.w + a2.w;
  ob.x = b0.x + b1.x + b2.x; ob.y = b0.y + b1.y + b2.y;
  ob.z = b0.z + b1.z + b2.z; ob.w = b0.w + b1.w + b2.w;
  float* op = out + (size_t)t * 2048 + c;
  *(float4*)op = oa;
  *(float4*)(op + 4) = ob;
}

extern "C" void kernel_launch(void* const* d_in, const int* in_sizes, int n_in,
                              void* d_out, int out_size, void* d_ws, size_t ws_size,
                              hipStream_t stream) {
  const float* x   = (const float*)d_in[0];
  const float* gw  = (const float*)d_in[1];
  const float* w1  = (const float*)d_in[2];
  const float* w2  = (const float*)d_in[3];
  const float* w3  = (const float*)d_in[4];
  const float* ws1 = (const float*)d_in[5];
  const float* ws2 = (const float*)d_in[6];
  const float* ws3 = (const float*)d_in[7];
  float* out = (float*)d_out;

  // ---- workspace layout (~190 MB, under previous 214 MB footprint) ----
  char* p = (char*)d_ws;
  int*   counts     = (int*)p;                 // 16 ints
  int*   cursor     = (int*)(p + 64);          // 16 ints
  int*   offs       = (int*)(p + 128);         // 10 ints
  int*   sel        = (int*)(p + 1024);        // 8192 ints
  float* sco        = (float*)(p + 1024 + 32768);
  int*   token_rows = (int*)(p + 1024 + 65536); // 12288 ints
  char* big = p + (1 << 20);
  __bf16* w13  = (__bf16*)big;                                              // 75,497,472 B
  __bf16* w2c  = (__bf16*)(big + 75497472ull);                              // 37,748,736 B
  __bf16* xg   = (__bf16*)(big + 75497472ull + 37748736ull);                // 50,331,648 B
  __bf16* hbuf = (__bf16*)(big + 75497472ull + 37748736ull + 50331648ull);  // 25,165,824 B
  float*  c2a  = (float*)w13;   // overlay: w13 dead after GEMM1 (8192*2048*4 = 67.1 MB <= 75.5 MB)
  float*  c2b  = (float*)xg;    // overlay: xg dead after GEMM1 (4096*2048*4 = 33.5 MB <= 50.3 MB)

  hipMemsetAsync(p, 0, 256, stream);  // counts + cursors

  convert_w<<<27648, 256, 0, stream>>>(w1, w2, w3, ws1, ws2, ws3, w13, w2c);
  router_k<<<TTOK / 4, 256, 0, stream>>>(x, gw, sel, sco, counts);
  scan_k<<<1, 64, 0, stream>>>(counts, offs);
  gather_k<<<TTOK, 256, 0, stream>>>(x, sel, sco, offs, cursor, token_rows, xg);
  gemm_nt<0><<<dim3(16, 8, 9), 512, 0, stream>>>(xg, w13, hbuf, nullptr, nullptr, offs, 2048, 2048);
  gemm_nt<1><<<dim3(16, 8, 9), 512, 0, stream>>>(hbuf, w2c, nullptr, c2a, c2b, offs, 1024, 2048);
  combine_k<<<TTOK, 256, 0, stream>>>(c2a, c2b, token_rows, out);
}

// Round 3
// 741.599 us; speedup vs baseline: 1.0493x; 1.0493x over previous
//
#include <hip/hip_runtime.h>
#include <hip/hip_bf16.h>
#include <cstdint>

// ---- problem constants (bs=4, slen=1024 -> T=4096; dim=2048; hidden=1024; E=8; top-2) ----
#define TTOK   4096
#define DIM    2048
#define HID    1024
#define NEXP   8          // routed experts
#define GROWS  12288      // TTOK*2 routed rows + TTOK shared rows

typedef __attribute__((ext_vector_type(8))) __bf16 bf16x8;
typedef __attribute__((ext_vector_type(4))) float  f32x4;

__device__ __forceinline__ void glds16(const void* g, void* l) {
  __builtin_amdgcn_global_load_lds((const __attribute__((address_space(1))) void*)g,
                                   (__attribute__((address_space(3))) void*)l,
                                   16, 0, 0);
}

// ---------------- merged weight-convert + router (independent work, one dispatch) ----------------
// Convert part (blocks [0, 27648)):
//   w13cat (9 x 2048 x 2048): rows INTERLEAVED per expert: new_r = 2j -> w1[j], 2j+1 -> w3[j],
//   so GEMM1 output col pairs (2j,2j+1) = (h1_j,h3_j) -> silu fused in GEMM1 epilogue via shfl_xor(1).
//   w2cat (9 x 2048 x 1024) plain bf16 cast.
// Router part (blocks [27648, 28672)): one wave per token, fp32 logits, sigmoid, top-2.
__global__ void convert_router_k(const float* __restrict__ w1, const float* __restrict__ w2,
                                 const float* __restrict__ w3, const float* __restrict__ ws1,
                                 const float* __restrict__ ws2, const float* __restrict__ ws3,
                                 __bf16* __restrict__ w13, __bf16* __restrict__ w2c,
                                 const float* __restrict__ x, const float* __restrict__ gw,
                                 int* __restrict__ sel, float* __restrict__ sco,
                                 int* __restrict__ counts) {
  const int N1 = 9 * 2048 * 2048 / 8;   // 16B-out chunks for w13
  const int N2 = 9 * 2048 * 1024 / 8;   // chunks for w2c
  const int CONV_BLOCKS = (N1 + N2) / 256;  // 27648

  if (blockIdx.x < (unsigned)CONV_BLOCKS) {
    int s = blockIdx.x * 256 + threadIdx.x;
    const float* src;
    __bf16* dst;
    if (s < N1) {
      int e  = s / 524288;            // 2048*2048/8
      int r  = (s % 524288) / 256;    // source row 0..2047
      int c  = (s % 256) * 8;
      int nr;
      if (r < 1024) { src = (e < 8 ? w1 + ((size_t)e * 1024 + r) * 2048 : ws1 + (size_t)r * 2048) + c;
                      nr = 2 * r; }
      else          { src = (e < 8 ? w3 + ((size_t)e * 1024 + (r - 1024)) * 2048 : ws3 + (size_t)(r - 1024) * 2048) + c;
                      nr = 2 * (r - 1024) + 1; }
      dst = w13 + ((size_t)e * 2048 + nr) * 2048 + c;
    } else {
      int s2 = s - N1;
      int e  = s2 / 262144;           // 2048*1024/8
      int r  = (s2 % 262144) / 128;   // row (d) 0..2047
      int c  = (s2 % 128) * 8;
      src = (e < 8 ? w2 + ((size_t)e * 2048 + r) * 1024 : ws2 + (size_t)r * 1024) + c;
      dst = w2c + ((size_t)e * 2048 + r) * 1024 + c;
    }
    float4 a = *(const float4*)(src);
    float4 b = *(const float4*)(src + 4);
    bf16x8 o;
    o[0]=(__bf16)a.x; o[1]=(__bf16)a.y; o[2]=(__bf16)a.z; o[3]=(__bf16)a.w;
    o[4]=(__bf16)b.x; o[5]=(__bf16)b.y; o[6]=(__bf16)b.z; o[7]=(__bf16)b.w;
    *(bf16x8*)dst = o;
    return;
  }

  // ---- router path ----
  int t    = (blockIdx.x - CONV_BLOCKS) * 4 + (threadIdx.x >> 6);
  int lane = threadIdx.x & 63;
  const float* xr = x + (size_t)t * DIM;
  float acc[NEXP];
  #pragma unroll
  for (int e = 0; e < NEXP; ++e) acc[e] = 0.f;
  for (int d = lane * 4; d < DIM; d += 256) {
    float4 xv = *(const float4*)(xr + d);
    #pragma unroll
    for (int e = 0; e < NEXP; ++e) {
      float4 gv = *(const float4*)(gw + (size_t)e * DIM + d);
      acc[e] += xv.x * gv.x + xv.y * gv.y + xv.z * gv.z + xv.w * gv.w;
    }
  }
  #pragma unroll
  for (int off = 32; off; off >>= 1)
    #pragma unroll
    for (int e = 0; e < NEXP; ++e) acc[e] += __shfl_xor(acc[e], off);
  if (lane == 0) {
    float s[NEXP];
    #pragma unroll
    for (int e = 0; e < NEXP; ++e) s[e] = 1.f / (1.f + expf(-acc[e]));
    int e0 = 0;
    #pragma unroll
    for (int e = 1; e < NEXP; ++e) if (s[e] > s[e0]) e0 = e;
    int e1 = (e0 == 0) ? 1 : 0;
    #pragma unroll
    for (int e = 0; e < NEXP; ++e) if (e != e0 && s[e] > s[e1]) e1 = e;
    sel[2 * t] = e0; sel[2 * t + 1] = e1;
    sco[2 * t] = s[e0]; sco[2 * t + 1] = s[e1];
    atomicAdd(&counts[e0], 1); atomicAdd(&counts[e1], 1);
  }
}

// ---------------- exclusive scan over 9 segments (expert 8 = shared, count TTOK) ----------------
__global__ void scan_k(const int* __restrict__ counts, int* __restrict__ offs) {
  if (threadIdx.x == 0 && blockIdx.x == 0) {
    int o = 0;
    for (int e = 0; e < NEXP; ++e) { offs[e] = o; o += counts[e]; }
    offs[NEXP] = o;            // == 8192
    offs[NEXP + 1] = o + TTOK; // == 12288
  }
}

// ---------------- gather: write score-scaled bf16 rows into compact segments ----------------
__global__ void gather_k(const float* __restrict__ x, const int* __restrict__ sel,
                         const float* __restrict__ sco, const int* __restrict__ offs,
                         int* __restrict__ cursor, int* __restrict__ token_rows,
                         __bf16* __restrict__ xg) {
  __shared__ int   rows[3];
  __shared__ float ss[3];
  int t = blockIdx.x;
  if (threadIdx.x == 0) {
    int e0 = sel[2 * t], e1 = sel[2 * t + 1];
    int r0 = offs[e0] + atomicAdd(&cursor[e0], 1);
    int r1 = offs[e1] + atomicAdd(&cursor[e1], 1);
    int r2 = 8192 + t; // shared segment starts at 8192 always
    rows[0] = r0; rows[1] = r1; rows[2] = r2;
    ss[0] = sco[2 * t]; ss[1] = sco[2 * t + 1]; ss[2] = 1.0f;
    token_rows[3 * t] = r0; token_rows[3 * t + 1] = r1; token_rows[3 * t + 2] = r2;
  }
  __syncthreads();
  int c = threadIdx.x * 8;
  float4 v0 = *(const float4*)(x + (size_t)t * DIM + c);
  float4 v1 = *(const float4*)(x + (size_t)t * DIM + c + 4);
  #pragma unroll
  for (int j = 0; j < 3; ++j) {
    float s = ss[j];
    bf16x8 o;
    o[0]=(__bf16)(v0.x*s); o[1]=(__bf16)(v0.y*s); o[2]=(__bf16)(v0.z*s); o[3]=(__bf16)(v0.w*s);
    o[4]=(__bf16)(v1.x*s); o[5]=(__bf16)(v1.y*s); o[6]=(__bf16)(v1.z*s); o[7]=(__bf16)(v1.w*s);
    *(bf16x8*)(xg + (size_t)rows[j] * DIM + c) = o;
  }
}

// ---------------- grouped NT GEMM, 128x128 tile, BK=64 (PROVEN R1 core) ----------------
// 2-PHASE DOUBLE-BUFFERED pipeline: stage tile t+1 into buf^1 BEFORE computing tile t,
// single __syncthreads per K-step; loads fly during MFMA phase (MfmaUtil 23%, measured).
// 64 KiB LDS + 256 threads -> 2 blocks/CU of TLP across the barrier drain.
// XCD-aware bijective block swizzle: flat&7 -> XCD chunk, bm fastest within chunk.
// LDS: chunk j (16B) of tile-row r stored at slot j^(r&7); staging permutes the GLOBAL chunk
// fetched per lane (glds16 LDS dest is base+lane*16, fixed — m104). Measured 0 bank conflicts.
// EPI=0: fused silu(h1)*h3 epilogue (w13 rows interleaved), writes bf16 h (GROWS x 1024).
// EPI=1: fp32 stores into split c2 buffers (no atomics).
template <int EPI>
__launch_bounds__(256)
__global__ void gemm_nt(const __bf16* __restrict__ A, const __bf16* __restrict__ Bw,
                        __bf16* __restrict__ Hb, float* __restrict__ c2a, float* __restrict__ c2b,
                        const int* __restrict__ offs, int K_, int N_) {
  int z  = blockIdx.z;
  int o0 = offs[z];
  int ne = offs[z + 1] - o0;

  int flat = blockIdx.y * 32 + blockIdx.x;       // 0..511, ascending in dispatch order
  int nid  = (flat & 7) * 64 + (flat >> 3);      // bijective (512 % 8 == 0)
  int bm   = nid & 31;
  int bn   = nid >> 5;

  if (bm * 128 >= ne) return;

  const __bf16* Aseg = A  + (size_t)(o0 + bm * 128) * K_;
  const __bf16* Bseg = Bw + ((size_t)z * N_ + bn * 128) * K_;

  __shared__ __align__(16) __bf16 sA[2][128 * 64];
  __shared__ __align__(16) __bf16 sB[2][128 * 64];

  int tid  = threadIdx.x;
  int wave = tid >> 6, lane = tid & 63;
  int wm = wave & 1, wn = wave >> 1;
  int fr = lane & 15;   // fragment row (m for A, n for B, also out col)
  int fq = lane >> 4;   // quad
  int sw = fr & 7;      // lane-constant XOR swizzle (16 | row strides)

  f32x4 acc[4][4];
  #pragma unroll
  for (int i = 0; i < 4; ++i)
    #pragma unroll
    for (int j = 0; j < 4; ++j) acc[i][j] = (f32x4){0.f, 0.f, 0.f, 0.f};

#define STAGE(buf, kbase)                                                     \
  {                                                                           \
    _Pragma("unroll")                                                         \
    for (int it = 0; it < 4; ++it) {                                          \
      int s   = it * 256 + tid;                                               \
      int row = s >> 3;                                                       \
      int c8  = (s & 7) ^ (row & 7);                                          \
      glds16(Aseg + (size_t)row * K_ + (kbase) + c8 * 8, &sA[buf][s * 8]);    \
      glds16(Bseg + (size_t)row * K_ + (kbase) + c8 * 8, &sB[buf][s * 8]);    \
    }                                                                         \
  }

  // prologue: stage tile 0 into buf 0 (syncthreads drains vmcnt)
  STAGE(0, 0)
  __syncthreads();

  const int nk = K_ >> 6;
  for (int t = 0; t < nk; ++t) {
    int cur = t & 1;
    // issue next tile's loads FIRST — they fly during the MFMA phase below
    if (t + 1 < nk) STAGE(cur ^ 1, (t + 1) << 6)

    const __bf16* rAbase = &sA[cur][(wm * 64 + fr) * 64];
    const __bf16* rBbase = &sB[cur][(wn * 64 + fr) * 64];
    #pragma unroll
    for (int kk = 0; kk < 2; ++kk) {
      int slot = ((kk * 4 + fq) ^ sw) * 8;
      bf16x8 af[4], bb[4];
      #pragma unroll
      for (int i = 0; i < 4; ++i) af[i] = *(const bf16x8*)(rAbase + i * 16 * 64 + slot);
      #pragma unroll
      for (int i = 0; i < 4; ++i) bb[i] = *(const bf16x8*)(rBbase + i * 16 * 64 + slot);
      #pragma unroll
      for (int mi = 0; mi < 4; ++mi)
        #pragma unroll
        for (int ni = 0; ni < 4; ++ni)
          acc[mi][ni] = __builtin_amdgcn_mfma_f32_16x16x32_bf16(af[mi], bb[ni], acc[mi][ni], 0, 0, 0);
    }
    // one barrier per K-step: (a) all waves done reading buf[cur] before next iter stages
    // into it; (b) compiler-emitted vmcnt(0) drain ensures buf[cur^1] landed before reads.
    __syncthreads();
  }
#undef STAGE

  // epilogue: C/D layout col = lane&15 (=fr), row = fq*4 + r   [m89/m91 verified]
  #pragma unroll
  for (int mi = 0; mi < 4; ++mi) {
    #pragma unroll
    for (int r = 0; r < 4; ++r) {
      int rl = bm * 128 + wm * 64 + mi * 16 + fq * 4 + r;
      bool ok = rl < ne;
      int grow = o0 + rl;
      if (EPI == 0) {
        // fused silu: col pairs (2j,2j+1) = (h1_j, h3_j); lane parity == col parity
        #pragma unroll
        for (int ni = 0; ni < 4; ++ni) {
          float v = acc[mi][ni][r];
          float o = __shfl_xor(v, 1);          // partner holds the other half of (h1,h3) pair
          float h1 = (fr & 1) ? o : v;
          float h3 = (fr & 1) ? v : o;
          float g  = h1 / (1.f + expf(-h1)) * h3;
          if (ok && !(fr & 1)) {
            int hcol = bn * 64 + wn * 32 + ni * 8 + (fr >> 1);
            Hb[(size_t)grow * 1024 + hcol] = (__bf16)g;
          }
        }
      } else {
        if (ok) {
          float* dst = (grow < 8192) ? (c2a + (size_t)grow * 2048)
                                     : (c2b + (size_t)(grow - 8192) * 2048);
          #pragma unroll
          for (int ni = 0; ni < 4; ++ni) {
            int col = bn * 128 + wn * 64 + ni * 16 + fr;
            dst[col] = acc[mi][ni][r];
          }
        }
      }
    }
  }
}

// ---------------- combine: out[t] = c2[r0] + c2[r1] + c2[r2] (fp32, deterministic) ----------------
__global__ void combine_k(const float* __restrict__ c2a, const float* __restrict__ c2b,
                          const int* __restrict__ token_rows, float* __restrict__ out) {
  __shared__ int rr[3];
  int t = blockIdx.x;
  if (threadIdx.x < 3) rr[threadIdx.x] = token_rows[3 * t + threadIdx.x];
  __syncthreads();
  int c = threadIdx.x * 8;
  const float* p0 = c2a + (size_t)rr[0] * 2048 + c;
  const float* p1 = c2a + (size_t)rr[1] * 2048 + c;
  const float* p2 = c2b + (size_t)(rr[2] - 8192) * 2048 + c;
  float4 a0 = *(const float4*)p0,       a1 = *(const float4*)p1,       a2 = *(const float4*)p2;
  float4 b0 = *(const float4*)(p0 + 4), b1 = *(const float4*)(p1 + 4), b2 = *(const float4*)(p2 + 4);
  float4 oa, ob;
  oa.x = a0.x + a1.x + a2.x; oa.y = a0.y + a1.y + a2.y;
  oa.z = a0.z + a1.z + a2.z; oa.w = a0.w + a1.w + a2.w;
  ob.x = b0.x + b1.x + b2.x; ob.y = b0.y + b1.y + b2.y;
  ob.z = b0.z + b1.z + b2.z; ob.w = b0.w + b1.w + b2.w;
  float* op = out + (size_t)t * 2048 + c;
  *(float4*)op = oa;
  *(float4*)(op + 4) = ob;
}

extern "C" void kernel_launch(void* const* d_in, const int* in_sizes, int n_in,
                              void* d_out, int out_size, void* d_ws, size_t ws_size,
                              hipStream_t stream) {
  const float* x   = (const float*)d_in[0];
  const float* gw  = (const float*)d_in[1];
  const float* w1  = (const float*)d_in[2];
  const float* w2  = (const float*)d_in[3];
  const float* w3  = (const float*)d_in[4];
  const float* ws1 = (const float*)d_in[5];
  const float* ws2 = (const float*)d_in[6];
  const float* ws3 = (const float*)d_in[7];
  float* out = (float*)d_out;

  // ---- workspace layout (~190 MB) ----
  char* p = (char*)d_ws;
  int*   counts     = (int*)p;                 // 16 ints
  int*   cursor     = (int*)(p + 64);          // 16 ints
  int*   offs       = (int*)(p + 128);         // 10 ints
  int*   sel        = (int*)(p + 1024);        // 8192 ints
  float* sco        = (float*)(p + 1024 + 32768);
  int*   token_rows = (int*)(p + 1024 + 65536); // 12288 ints
  char* big = p + (1 << 20);
  __bf16* w13  = (__bf16*)big;                                              // 75,497,472 B
  __bf16* w2c  = (__bf16*)(big + 75497472ull);                              // 37,748,736 B
  __bf16* xg   = (__bf16*)(big + 75497472ull + 37748736ull);                // 50,331,648 B
  __bf16* hbuf = (__bf16*)(big + 75497472ull + 37748736ull + 50331648ull);  // 25,165,824 B
  float*  c2a  = (float*)w13;   // overlay: w13 dead after GEMM1 (8192*2048*4 = 67.1 MB <= 75.5 MB)
  float*  c2b  = (float*)xg;    // overlay: xg dead after GEMM1 (4096*2048*4 = 33.5 MB <= 50.3 MB)

  hipMemsetAsync(p, 0, 256, stream);  // counts + cursors

  convert_router_k<<<27648 + TTOK / 4, 256, 0, stream>>>(w1, w2, w3, ws1, ws2, ws3, w13, w2c,
                                                         x, gw, sel, sco, counts);
  scan_k<<<1, 64, 0, stream>>>(counts, offs);
  gather_k<<<TTOK, 256, 0, stream>>>(x, sel, sco, offs, cursor, token_rows, xg);
  gemm_nt<0><<<dim3(32, 16, 9), 256, 0, stream>>>(xg, w13, hbuf, nullptr, nullptr, offs, 2048, 2048);
  gemm_nt<1><<<dim3(32, 16, 9), 256, 0, stream>>>(hbuf, w2c, nullptr, c2a, c2b, offs, 1024, 2048);
  combine_k<<<TTOK, 256, 0, stream>>>(c2a, c2b, token_rows, out);
}